// Round 1
// baseline (1599.768 us; speedup 1.0000x reference)
//
#include <hip/hip_runtime.h>

#define IN_C 8
#define HID_C 64
#define OUT_C 32

// ---------------------------------------------------------------------------
// Phase 1: per-edge scatter of x[src] into agg1[dst] (+ degree count).
// 1 thread per edge; 8-channel float atomics into an L2-resident 3.2MB buffer.
// ---------------------------------------------------------------------------
__global__ __launch_bounds__(256) void edges1_kernel(
    const int* __restrict__ src, const int* __restrict__ dst,
    const float* __restrict__ x, float* __restrict__ agg1,
    int* __restrict__ cnt, int E)
{
    int e = blockIdx.x * blockDim.x + threadIdx.x;
    if (e >= E) return;
    int s = src[e];
    int d = dst[e];
    atomicAdd(&cnt[d], 1);
    const float4* xs = (const float4*)(x + (size_t)s * IN_C);
    float4 a = xs[0];
    float4 b = xs[1];
    float* ag = agg1 + (size_t)d * IN_C;
    atomicAdd(ag + 0, a.x); atomicAdd(ag + 1, a.y);
    atomicAdd(ag + 2, a.z); atomicAdd(ag + 3, a.w);
    atomicAdd(ag + 4, b.x); atomicAdd(ag + 5, b.y);
    atomicAdd(ag + 6, b.z); atomicAdd(ag + 7, b.w);
}

// ---------------------------------------------------------------------------
// Phase 2 (fused node compute):
//   h = relu(mean1 @ W1_l.T + b1 + x @ W1_r.T)        (64ch, kept in LDS only)
//   p = h @ W2_l.T                                     (32ch, neighbor message)
//   out = b2 + h @ W2_r.T                              (32ch, self term init)
//   inv_cnt = 1 / max(cnt, 1)
// Block = 256 threads = 4 nodes x 64 channel-threads.
// ---------------------------------------------------------------------------
__global__ __launch_bounds__(256) void nodes1_kernel(
    const float* __restrict__ x, const float* __restrict__ agg1,
    const int* __restrict__ cnt,
    const float* __restrict__ W1l, const float* __restrict__ W1r,
    const float* __restrict__ b1,
    const float* __restrict__ W2l, const float* __restrict__ W2r,
    const float* __restrict__ b2,
    float* __restrict__ p, float* __restrict__ out,
    float* __restrict__ inv_cnt, int N)
{
    __shared__ float hl[4][HID_C];
    int tid = threadIdx.x;
    int local_n = tid >> 6;       // 0..3
    int c = tid & 63;             // channel
    int n = blockIdx.x * 4 + local_n;

    if (n < N) {
        float icnt = 1.0f / (float)max(cnt[n], 1);
        const float* xp = x + (size_t)n * IN_C;
        const float* ap = agg1 + (size_t)n * IN_C;
        float acc = b1[c];
        #pragma unroll
        for (int k = 0; k < IN_C; ++k) {
            float mean = ap[k] * icnt;
            acc += mean * W1l[c * IN_C + k] + xp[k] * W1r[c * IN_C + k];
        }
        hl[local_n][c] = fmaxf(acc, 0.0f);
        if (c == 0) inv_cnt[n] = icnt;
    }
    __syncthreads();
    if (n < N && c < OUT_C) {
        float accp = 0.0f;
        float acco = b2[c];
        #pragma unroll
        for (int k = 0; k < HID_C; ++k) {
            float h = hl[local_n][k];
            accp += h * W2l[c * HID_C + k];
            acco += h * W2r[c * HID_C + k];
        }
        p[(size_t)n * OUT_C + c]   = accp;
        out[(size_t)n * OUT_C + c] = acco;
    }
}

// ---------------------------------------------------------------------------
// Phase 3: per-edge scatter of pre-scaled p[src] into out[dst].
// mean is folded in: each contribution is multiplied by inv_cnt[dst].
// 8 threads per edge, each owning a float4 (4 channels).
// ---------------------------------------------------------------------------
__global__ __launch_bounds__(256) void edges2_kernel(
    const int* __restrict__ src, const int* __restrict__ dst,
    const float* __restrict__ p, const float* __restrict__ inv_cnt,
    float* __restrict__ out, int E)
{
    int gid = blockIdx.x * blockDim.x + threadIdx.x;
    int e = gid >> 3;
    if (e >= E) return;
    int q = gid & 7;
    int s = src[e];
    int d = dst[e];
    float ic = inv_cnt[d];
    float4 v = *(const float4*)(p + (size_t)s * OUT_C + q * 4);
    float* op = out + (size_t)d * OUT_C + q * 4;
    atomicAdd(op + 0, v.x * ic);
    atomicAdd(op + 1, v.y * ic);
    atomicAdd(op + 2, v.z * ic);
    atomicAdd(op + 3, v.w * ic);
}

extern "C" void kernel_launch(void* const* d_in, const int* in_sizes, int n_in,
                              void* d_out, int out_size, void* d_ws, size_t ws_size,
                              hipStream_t stream) {
    const float* x   = (const float*)d_in[0];
    const int*   ei  = (const int*)d_in[1];
    const float* W1l = (const float*)d_in[2];
    const float* W1r = (const float*)d_in[3];
    const float* b1  = (const float*)d_in[4];
    const float* W2l = (const float*)d_in[5];
    const float* W2r = (const float*)d_in[6];
    const float* b2  = (const float*)d_in[7];
    float* out = (float*)d_out;

    int N = in_sizes[0] / IN_C;
    int E = in_sizes[1] / 2;
    const int* src = ei;
    const int* dst = ei + E;

    // Workspace layout (all float-sized slots):
    //   agg1    : N * 8  floats   (offset 0)
    //   cnt     : N      ints     (offset N*8)
    //   inv_cnt : N      floats   (offset N*9)
    //   p       : N * 32 floats   (offset N*10)
    char* ws = (char*)d_ws;
    float* agg1    = (float*)ws;
    int*   cnt     = (int*)  (ws + (size_t)N * IN_C * 4);
    float* inv_cnt = (float*)(ws + (size_t)N * (IN_C + 1) * 4);
    float* p       = (float*)(ws + (size_t)N * (IN_C + 2) * 4);

    // Zero agg1 + cnt (contiguous) every call — deterministic re-init.
    hipMemsetAsync(d_ws, 0, (size_t)N * (IN_C + 1) * 4, stream);

    const int blk = 256;
    edges1_kernel<<<(E + blk - 1) / blk, blk, 0, stream>>>(src, dst, x, agg1, cnt, E);
    nodes1_kernel<<<(N + 3) / 4, blk, 0, stream>>>(x, agg1, cnt,
                                                   W1l, W1r, b1, W2l, W2r, b2,
                                                   p, out, inv_cnt, N);
    long long t2 = (long long)E * 8;
    edges2_kernel<<<(int)((t2 + blk - 1) / blk), blk, 0, stream>>>(src, dst, p, inv_cnt, out, E);
}

// Round 2
// 560.133 us; speedup vs baseline: 2.8560x; 2.8560x over previous
//
#include <hip/hip_runtime.h>

#define IN_C 8
#define HID_C 64
#define OUT_C 32

// ---------------------------------------------------------------------------
// K1: histogram of dst degrees (int atomics, 1 per edge).
// ---------------------------------------------------------------------------
__global__ __launch_bounds__(256) void hist_kernel(
    const int* __restrict__ dst, int* __restrict__ cnt, int E)
{
    int e = blockIdx.x * blockDim.x + threadIdx.x;
    if (e < E) atomicAdd(&cnt[dst[e]], 1);
}

// ---------------------------------------------------------------------------
// K2: assign contiguous CSR segment bases via a global cursor.
// Wave-level inclusive scan -> 1 atomic per 64 nodes. Also computes inv_cnt.
// ---------------------------------------------------------------------------
__global__ __launch_bounds__(256) void base_kernel(
    const int* __restrict__ cnt, int* __restrict__ base, int* __restrict__ wpos,
    float* __restrict__ inv_cnt, int* __restrict__ cursor, int N)
{
    int n = blockIdx.x * blockDim.x + threadIdx.x;
    int lane = threadIdx.x & 63;
    int c = (n < N) ? cnt[n] : 0;

    // inclusive wave scan of c
    int v = c;
    #pragma unroll
    for (int off = 1; off < 64; off <<= 1) {
        int t = __shfl_up(v, off);
        if (lane >= off) v += t;
    }
    int total = __shfl(v, 63);
    int waveBase = 0;
    if (lane == 63 && total > 0) waveBase = atomicAdd(cursor, total);
    waveBase = __shfl(waveBase, 63);

    if (n < N) {
        int b = waveBase + v - c;   // exclusive prefix within wave + global base
        base[n] = b;
        wpos[n] = b;
        inv_cnt[n] = 1.0f / (float)max(c, 1);
    }
}

// ---------------------------------------------------------------------------
// K3: fill CSR adjacency: csr_src[slot] = src for each edge grouped by dst.
// ---------------------------------------------------------------------------
__global__ __launch_bounds__(256) void fill_kernel(
    const int* __restrict__ src, const int* __restrict__ dst,
    int* __restrict__ wpos, int* __restrict__ csr_src, int E)
{
    int e = blockIdx.x * blockDim.x + threadIdx.x;
    if (e < E) {
        int pos = atomicAdd(&wpos[dst[e]], 1);
        csr_src[pos] = src[e];
    }
}

// ---------------------------------------------------------------------------
// K4 (fused layer-1 node compute, gather-based, one wave per node):
//   mean   = (1/deg) * sum_{s in N(n)} x[s]              (8ch gather)
//   h      = relu(mean @ W1_l.T + b1 + x @ W1_r.T)       (64ch, LDS only)
//   p      = h @ W2_l.T                                  (32ch message)
//   out    = b2 + h @ W2_r.T                             (32ch self term)
// Block = 256 threads = 4 waves = 4 nodes.
// Gather: lane l -> neighbor (l>>3), channel (l&7); shfl-reduce 8 groups.
// ---------------------------------------------------------------------------
__global__ __launch_bounds__(256) void layer1_kernel(
    const float* __restrict__ x, const int* __restrict__ csr_src,
    const int* __restrict__ base, const int* __restrict__ cnt,
    const float* __restrict__ inv_cnt,
    const float* __restrict__ W1l, const float* __restrict__ W1r,
    const float* __restrict__ b1,
    const float* __restrict__ W2l, const float* __restrict__ W2r,
    const float* __restrict__ b2,
    float* __restrict__ p, float* __restrict__ out, int N)
{
    __shared__ float hl[4][HID_C];
    int tid = threadIdx.x;
    int w = tid >> 6;
    int l = tid & 63;
    int n = blockIdx.x * 4 + w;

    int deg = 0, b0 = 0;
    float icnt = 1.0f;
    if (n < N) { deg = cnt[n]; b0 = base[n]; icnt = inv_cnt[n]; }

    // 8-channel gather-sum over neighbors
    int c8 = l & 7;
    float accg = 0.0f;
    for (int it = (l >> 3); it < deg; it += 8) {
        int s = csr_src[b0 + it];
        accg += x[(size_t)s * IN_C + c8];
    }
    accg += __shfl_xor(accg, 8);
    accg += __shfl_xor(accg, 16);
    accg += __shfl_xor(accg, 32);
    float meanv = accg * icnt;           // lane k (k<8) holds channel-k mean

    float mk[8];
    #pragma unroll
    for (int k = 0; k < 8; ++k) mk[k] = __shfl(meanv, k);

    float h = 0.0f;
    if (n < N) {
        const float* xp = x + (size_t)n * IN_C;
        float acc = b1[l];
        #pragma unroll
        for (int k = 0; k < IN_C; ++k)
            acc += mk[k] * W1l[l * IN_C + k] + xp[k] * W1r[l * IN_C + k];
        h = fmaxf(acc, 0.0f);
    }
    hl[w][l] = h;
    __syncthreads();

    if (n < N && l < OUT_C) {
        float accp = 0.0f;
        float acco = b2[l];
        #pragma unroll
        for (int k = 0; k < HID_C; ++k) {
            float hv = hl[w][k];
            accp += hv * W2l[l * HID_C + k];
            acco += hv * W2r[l * HID_C + k];
        }
        p[(size_t)n * OUT_C + l]   = accp;
        out[(size_t)n * OUT_C + l] = acco;
    }
}

// ---------------------------------------------------------------------------
// K5 (layer-2 gather): out[n] = (1/deg) * sum p[src] + out_self[n].
// One wave per node; lane l -> neighbor parity (l>>5), channel (l&31);
// each half-wave issues one coalesced 128B row read per neighbor.
// ---------------------------------------------------------------------------
__global__ __launch_bounds__(256) void layer2_kernel(
    const float* __restrict__ p, const int* __restrict__ csr_src,
    const int* __restrict__ base, const int* __restrict__ cnt,
    const float* __restrict__ inv_cnt, float* __restrict__ out, int N)
{
    int tid = threadIdx.x;
    int w = tid >> 6;
    int l = tid & 63;
    int n = blockIdx.x * 4 + w;
    if (n >= N) return;

    int deg = cnt[n];
    int b0  = base[n];
    int half = l >> 5;
    int c = l & 31;

    float acc = 0.0f;
    for (int it = half; it < deg; it += 2) {
        int s = csr_src[b0 + it];
        acc += p[(size_t)s * OUT_C + c];
    }
    acc += __shfl_xor(acc, 32);

    if (half == 0) {
        size_t o = (size_t)n * OUT_C + c;
        out[o] = acc * inv_cnt[n] + out[o];
    }
}

extern "C" void kernel_launch(void* const* d_in, const int* in_sizes, int n_in,
                              void* d_out, int out_size, void* d_ws, size_t ws_size,
                              hipStream_t stream) {
    const float* x   = (const float*)d_in[0];
    const int*   ei  = (const int*)d_in[1];
    const float* W1l = (const float*)d_in[2];
    const float* W1r = (const float*)d_in[3];
    const float* b1  = (const float*)d_in[4];
    const float* W2l = (const float*)d_in[5];
    const float* W2r = (const float*)d_in[6];
    const float* b2  = (const float*)d_in[7];
    float* out = (float*)d_out;

    int N = in_sizes[0] / IN_C;
    int E = in_sizes[1] / 2;
    const int* src = ei;
    const int* dst = ei + E;

    // Workspace layout:
    //   cnt     : N ints        (zeroed)
    //   cursor  : 1 int         (zeroed)
    //   base    : N ints
    //   wpos    : N ints
    //   inv_cnt : N floats
    //   csr_src : E ints
    //   p       : N*OUT_C floats
    char* ws = (char*)d_ws;
    size_t off = 0;
    int*   cnt     = (int*)(ws + off); off += (size_t)N * 4;
    int*   cursor  = (int*)(ws + off); off += 4;
    int*   base    = (int*)(ws + off); off += (size_t)N * 4;
    int*   wpos    = (int*)(ws + off); off += (size_t)N * 4;
    float* inv_cnt = (float*)(ws + off); off += (size_t)N * 4;
    int*   csr_src = (int*)(ws + off); off += (size_t)E * 4;
    float* p       = (float*)(ws + off);

    // Zero cnt + cursor (contiguous prefix) every call.
    hipMemsetAsync(d_ws, 0, (size_t)(N + 1) * 4, stream);

    const int blk = 256;
    hist_kernel<<<(E + blk - 1) / blk, blk, 0, stream>>>(dst, cnt, E);
    base_kernel<<<(N + blk - 1) / blk, blk, 0, stream>>>(cnt, base, wpos, inv_cnt, cursor, N);
    fill_kernel<<<(E + blk - 1) / blk, blk, 0, stream>>>(src, dst, wpos, csr_src, E);
    layer1_kernel<<<(N + 3) / 4, blk, 0, stream>>>(x, csr_src, base, cnt, inv_cnt,
                                                   W1l, W1r, b1, W2l, W2r, b2, p, out, N);
    layer2_kernel<<<(N + 3) / 4, blk, 0, stream>>>(p, csr_src, base, cnt, inv_cnt, out, N);
}

// Round 3
// 382.442 us; speedup vs baseline: 4.1830x; 1.4646x over previous
//
#include <hip/hip_runtime.h>

#define IN_C 8
#define HID_C 64
#define OUT_C 32

// ---------------------------------------------------------------------------
// K1: histogram of dst degrees (4 edges/thread, int4 loads).
// ---------------------------------------------------------------------------
__global__ __launch_bounds__(256) void hist_kernel(
    const int* __restrict__ dst, int* __restrict__ cnt, int E)
{
    int i = blockIdx.x * blockDim.x + threadIdx.x;
    int e0 = i * 4;
    if (e0 + 3 < E) {
        int4 d4 = *(const int4*)(dst + e0);
        atomicAdd(&cnt[d4.x], 1); atomicAdd(&cnt[d4.y], 1);
        atomicAdd(&cnt[d4.z], 1); atomicAdd(&cnt[d4.w], 1);
    } else {
        for (int e = e0; e < E; ++e) atomicAdd(&cnt[dst[e]], 1);
    }
}

// ---------------------------------------------------------------------------
// K2: CSR segment bases via wave-scan + one cursor atomic per wave.
// ---------------------------------------------------------------------------
__global__ __launch_bounds__(256) void base_kernel(
    const int* __restrict__ cnt, int* __restrict__ base, int* __restrict__ wpos,
    int* __restrict__ cursor, int N)
{
    int n = blockIdx.x * blockDim.x + threadIdx.x;
    int lane = threadIdx.x & 63;
    int c = (n < N) ? cnt[n] : 0;

    int v = c;
    #pragma unroll
    for (int off = 1; off < 64; off <<= 1) {
        int t = __shfl_up(v, off);
        if (lane >= off) v += t;
    }
    int total = __shfl(v, 63);
    int waveBase = 0;
    if (lane == 63 && total > 0) waveBase = atomicAdd(cursor, total);
    waveBase = __shfl(waveBase, 63);

    if (n < N) {
        int b = waveBase + v - c;
        base[n] = b;
        wpos[n] = b;
    }
}

// ---------------------------------------------------------------------------
// K3: fill CSR adjacency (4 edges/thread).
// ---------------------------------------------------------------------------
__global__ __launch_bounds__(256) void fill_kernel(
    const int* __restrict__ src, const int* __restrict__ dst,
    int* __restrict__ wpos, int* __restrict__ csr_src, int E)
{
    int i = blockIdx.x * blockDim.x + threadIdx.x;
    int e0 = i * 4;
    if (e0 + 3 < E) {
        int4 s4 = *(const int4*)(src + e0);
        int4 d4 = *(const int4*)(dst + e0);
        csr_src[atomicAdd(&wpos[d4.x], 1)] = s4.x;
        csr_src[atomicAdd(&wpos[d4.y], 1)] = s4.y;
        csr_src[atomicAdd(&wpos[d4.z], 1)] = s4.z;
        csr_src[atomicAdd(&wpos[d4.w], 1)] = s4.w;
    } else {
        for (int e = e0; e < E; ++e)
            csr_src[atomicAdd(&wpos[dst[e]], 1)] = src[e];
    }
}

// ---------------------------------------------------------------------------
// K4: fused layer-1 + layer-2 projections. One wave per node, grid-strided.
// Weights live in REGISTERS per wave (preloaded once):
//   lane l: W1l/W1r row l (8+8 floats); W2 column c=l&31 of (l<32 ? W2l : W2r)
//   as 16 float4s.
// Per node: gather mean(x[nbrs]) -> h = relu(...) -> stage h in LDS ->
//   every lane dots h (uniform float4 broadcasts) with its W2 column ->
//   lanes 0-31 write p[n], lanes 32-63 write out_self[n].
// Uniform trip count so __syncthreads is safe.
// ---------------------------------------------------------------------------
__global__ __launch_bounds__(256) void layer1_kernel(
    const float* __restrict__ x, const int* __restrict__ csr_src,
    const int* __restrict__ base, const int* __restrict__ cnt,
    const float* __restrict__ W1l, const float* __restrict__ W1r,
    const float* __restrict__ b1,
    const float* __restrict__ W2l, const float* __restrict__ W2r,
    const float* __restrict__ b2,
    float* __restrict__ p, float* __restrict__ out, int N, int nwaves)
{
    __shared__ float hl[4][HID_C];
    int tid = threadIdx.x;
    int w = tid >> 6;
    int l = tid & 63;
    int waveId = blockIdx.x * 4 + w;

    // --- per-wave constant preloads (registers) ---
    float4 w1l_a = *(const float4*)(W1l + l * IN_C);
    float4 w1l_b = *(const float4*)(W1l + l * IN_C + 4);
    float4 w1r_a = *(const float4*)(W1r + l * IN_C);
    float4 w1r_b = *(const float4*)(W1r + l * IN_C + 4);
    int c = l & 31;
    const float* W2 = (l < 32) ? W2l : W2r;
    float4 w2q[16];
    #pragma unroll
    for (int r = 0; r < 16; ++r)
        w2q[r] = *(const float4*)(W2 + c * HID_C + r * 4);
    float bias1 = b1[l];
    float bias2 = (l < 32) ? 0.0f : b2[c];
    float* dstp = (l < 32) ? p : out;

    int c8 = l & 7;
    int T = (N + nwaves - 1) / nwaves;

    for (int t = 0; t < T; ++t) {
        int n = waveId + t * nwaves;
        bool active = (n < N);
        int deg = 0, b0 = 0;
        if (active) { deg = cnt[n]; b0 = base[n]; }
        float icnt = 1.0f / (float)max(deg, 1);

        // gather mean over neighbors: 8 lanes/neighbor, channel c8
        float accg = 0.0f;
        for (int it = (l >> 3); it < deg; it += 8)
            accg += x[(size_t)csr_src[b0 + it] * IN_C + c8];
        accg += __shfl_xor(accg, 8);
        accg += __shfl_xor(accg, 16);
        accg += __shfl_xor(accg, 32);
        float meanv = accg * icnt;
        float mk[8];
        #pragma unroll
        for (int k = 0; k < 8; ++k) mk[k] = __shfl(meanv, k);

        float h = 0.0f;
        if (active) {
            float4 xa = *(const float4*)(x + (size_t)n * IN_C);
            float4 xb = *(const float4*)(x + (size_t)n * IN_C + 4);
            float acc = bias1;
            acc += mk[0] * w1l_a.x + xa.x * w1r_a.x;
            acc += mk[1] * w1l_a.y + xa.y * w1r_a.y;
            acc += mk[2] * w1l_a.z + xa.z * w1r_a.z;
            acc += mk[3] * w1l_a.w + xa.w * w1r_a.w;
            acc += mk[4] * w1l_b.x + xb.x * w1r_b.x;
            acc += mk[5] * w1l_b.y + xb.y * w1r_b.y;
            acc += mk[6] * w1l_b.z + xb.z * w1r_b.z;
            acc += mk[7] * w1l_b.w + xb.w * w1r_b.w;
            h = fmaxf(acc, 0.0f);
        }
        hl[w][l] = h;
        __syncthreads();

        float acc2 = bias2;
        #pragma unroll
        for (int r = 0; r < 16; ++r) {
            float4 h4 = *(const float4*)&hl[w][r * 4];   // uniform -> broadcast
            acc2 += h4.x * w2q[r].x + h4.y * w2q[r].y
                  + h4.z * w2q[r].z + h4.w * w2q[r].w;
        }
        __syncthreads();

        if (active) dstp[(size_t)n * OUT_C + c] = acc2;
    }
}

// ---------------------------------------------------------------------------
// K5: layer-2 neighbor gather. One wave per node, grid-strided.
// lane l = (j = l>>3 neighbor sub-slot, q = l&7 channel-quad): float4 gathers,
// 8 neighbors x 1KB per iteration; 12-shfl tree reduces j; lanes 0-7 RMW out.
// ---------------------------------------------------------------------------
__global__ __launch_bounds__(256) void layer2_kernel(
    const float* __restrict__ p, const int* __restrict__ csr_src,
    const int* __restrict__ base, const int* __restrict__ cnt,
    float* __restrict__ out, int N, int nwaves)
{
    int tid = threadIdx.x;
    int w = tid >> 6;
    int l = tid & 63;
    int waveId = blockIdx.x * 4 + w;
    int j = l >> 3;
    int q = l & 7;

    for (int n = waveId; n < N; n += nwaves) {
        int deg = cnt[n];
        int b0 = base[n];
        float4 acc = make_float4(0.f, 0.f, 0.f, 0.f);
        for (int it = j; it < deg; it += 8) {
            int s = csr_src[b0 + it];
            float4 v = *(const float4*)(p + (size_t)s * OUT_C + q * 4);
            acc.x += v.x; acc.y += v.y; acc.z += v.z; acc.w += v.w;
        }
        #pragma unroll
        for (int m = 8; m <= 32; m <<= 1) {
            acc.x += __shfl_xor(acc.x, m);
            acc.y += __shfl_xor(acc.y, m);
            acc.z += __shfl_xor(acc.z, m);
            acc.w += __shfl_xor(acc.w, m);
        }
        if (l < 8) {
            float icnt = 1.0f / (float)max(deg, 1);
            float4* op = (float4*)(out + (size_t)n * OUT_C) + q;
            float4 o = *op;
            o.x += acc.x * icnt; o.y += acc.y * icnt;
            o.z += acc.z * icnt; o.w += acc.w * icnt;
            *op = o;
        }
    }
}

extern "C" void kernel_launch(void* const* d_in, const int* in_sizes, int n_in,
                              void* d_out, int out_size, void* d_ws, size_t ws_size,
                              hipStream_t stream) {
    const float* x   = (const float*)d_in[0];
    const int*   ei  = (const int*)d_in[1];
    const float* W1l = (const float*)d_in[2];
    const float* W1r = (const float*)d_in[3];
    const float* b1  = (const float*)d_in[4];
    const float* W2l = (const float*)d_in[5];
    const float* W2r = (const float*)d_in[6];
    const float* b2  = (const float*)d_in[7];
    float* out = (float*)d_out;

    int N = in_sizes[0] / IN_C;
    int E = in_sizes[1] / 2;
    const int* src = ei;
    const int* dst = ei + E;

    // Workspace: cnt[N] | cursor[1] | base[N] | wpos[N] | csr_src[E] | p[N*32]
    char* ws = (char*)d_ws;
    size_t off = 0;
    int*   cnt     = (int*)(ws + off); off += (size_t)N * 4;
    int*   cursor  = (int*)(ws + off); off += 4;
    int*   base    = (int*)(ws + off); off += (size_t)N * 4;
    int*   wpos    = (int*)(ws + off); off += (size_t)N * 4;
    int*   csr_src = (int*)(ws + off); off += (size_t)E * 4;
    float* p       = (float*)(ws + off);

    hipMemsetAsync(d_ws, 0, (size_t)(N + 1) * 4, stream);

    const int blk = 256;
    const int nblocks = 2048;               // 8192 waves, grid-strided
    const int nwaves = nblocks * 4;

    hist_kernel<<<(E / 4 + blk - 1) / blk, blk, 0, stream>>>(dst, cnt, E);
    base_kernel<<<(N + blk - 1) / blk, blk, 0, stream>>>(cnt, base, wpos, cursor, N);
    fill_kernel<<<(E / 4 + blk - 1) / blk, blk, 0, stream>>>(src, dst, wpos, csr_src, E);
    layer1_kernel<<<nblocks, blk, 0, stream>>>(x, csr_src, base, cnt,
                                               W1l, W1r, b1, W2l, W2r, b2,
                                               p, out, N, nwaves);
    layer2_kernel<<<nblocks, blk, 0, stream>>>(p, csr_src, base, cnt, out, N, nwaves);
}

// Round 4
// 343.358 us; speedup vs baseline: 4.6592x; 1.1138x over previous
//
#include <hip/hip_runtime.h>

#define IN_C 8
#define HID_C 64
#define OUT_C 32

// ---------------------------------------------------------------------------
// K1: histogram of dst degrees (4 edges/thread, int4 loads).
// ---------------------------------------------------------------------------
__global__ __launch_bounds__(256) void hist_kernel(
    const int* __restrict__ dst, int* __restrict__ cnt, int E)
{
    int i = blockIdx.x * blockDim.x + threadIdx.x;
    int e0 = i * 4;
    if (e0 + 3 < E) {
        int4 d4 = *(const int4*)(dst + e0);
        atomicAdd(&cnt[d4.x], 1); atomicAdd(&cnt[d4.y], 1);
        atomicAdd(&cnt[d4.z], 1); atomicAdd(&cnt[d4.w], 1);
    } else {
        for (int e = e0; e < E; ++e) atomicAdd(&cnt[dst[e]], 1);
    }
}

// ---------------------------------------------------------------------------
// K2: CSR segment bases via wave-scan + one cursor atomic per wave.
// ---------------------------------------------------------------------------
__global__ __launch_bounds__(256) void base_kernel(
    const int* __restrict__ cnt, int* __restrict__ base, int* __restrict__ wpos,
    int* __restrict__ cursor, int N)
{
    int n = blockIdx.x * blockDim.x + threadIdx.x;
    int lane = threadIdx.x & 63;
    int c = (n < N) ? cnt[n] : 0;

    int v = c;
    #pragma unroll
    for (int off = 1; off < 64; off <<= 1) {
        int t = __shfl_up(v, off);
        if (lane >= off) v += t;
    }
    int total = __shfl(v, 63);
    int waveBase = 0;
    if (lane == 63 && total > 0) waveBase = atomicAdd(cursor, total);
    waveBase = __shfl(waveBase, 63);

    if (n < N) {
        int b = waveBase + v - c;
        base[n] = b;
        wpos[n] = b;
    }
}

// ---------------------------------------------------------------------------
// K3: fill CSR adjacency (4 edges/thread).
// ---------------------------------------------------------------------------
__global__ __launch_bounds__(256) void fill_kernel(
    const int* __restrict__ src, const int* __restrict__ dst,
    int* __restrict__ wpos, int* __restrict__ csr_src, int E)
{
    int i = blockIdx.x * blockDim.x + threadIdx.x;
    int e0 = i * 4;
    if (e0 + 3 < E) {
        int4 s4 = *(const int4*)(src + e0);
        int4 d4 = *(const int4*)(dst + e0);
        csr_src[atomicAdd(&wpos[d4.x], 1)] = s4.x;
        csr_src[atomicAdd(&wpos[d4.y], 1)] = s4.y;
        csr_src[atomicAdd(&wpos[d4.z], 1)] = s4.z;
        csr_src[atomicAdd(&wpos[d4.w], 1)] = s4.w;
    } else {
        for (int e = e0; e < E; ++e)
            csr_src[atomicAdd(&wpos[dst[e]], 1)] = src[e];
    }
}

// ---------------------------------------------------------------------------
// K4: fused layer-1 + both layer-2 projections. One wave per node,
// grid-strided, NO BARRIERS (hl[w] is wave-local; DS ops complete in
// wave program order, so write->read->next-write needs no sync).
// Gather: lane = (slot = l>>1 in 0..31, q = l&1 channel-quad); deg<=32
// nodes issue ONE float4 gather instruction. xor-tree reduce over slot
// bits, one xor(1) quad exchange to assemble mean[0..7] per lane.
// W2 dot: 4 independent accumulator chains, uniform LDS float4 broadcasts.
// ---------------------------------------------------------------------------
__global__ __launch_bounds__(256) void layer1_kernel(
    const float* __restrict__ x, const int* __restrict__ csr_src,
    const int* __restrict__ base, const int* __restrict__ cnt,
    const float* __restrict__ W1l, const float* __restrict__ W1r,
    const float* __restrict__ b1,
    const float* __restrict__ W2l, const float* __restrict__ W2r,
    const float* __restrict__ b2,
    float* __restrict__ p, float* __restrict__ out, int N, int nwaves)
{
    __shared__ float hl[4][HID_C];
    int tid = threadIdx.x;
    int w = tid >> 6;
    int l = tid & 63;
    int waveId = blockIdx.x * 4 + w;

    // --- per-wave constant preloads (registers) ---
    float4 w1l_a = *(const float4*)(W1l + l * IN_C);
    float4 w1l_b = *(const float4*)(W1l + l * IN_C + 4);
    float4 w1r_a = *(const float4*)(W1r + l * IN_C);
    float4 w1r_b = *(const float4*)(W1r + l * IN_C + 4);
    int c = l & 31;
    const float* W2 = (l < 32) ? W2l : W2r;
    float4 w2q[16];
    #pragma unroll
    for (int r = 0; r < 16; ++r)
        w2q[r] = *(const float4*)(W2 + c * HID_C + r * 4);
    float bias1 = b1[l];
    float bias2 = (l < 32) ? 0.0f : b2[c];
    float* dstp = (l < 32) ? p : out;

    int slot = l >> 1;
    int q = l & 1;

    for (int n = waveId; n < N; n += nwaves) {
        int deg = cnt[n];
        int b0 = base[n];
        float icnt = 1.0f / (float)max(deg, 1);

        // one float4 gather instruction covers 32 neighbors
        float4 g = make_float4(0.f, 0.f, 0.f, 0.f);
        for (int it = slot; it < deg; it += 32) {
            int s = csr_src[b0 + it];
            float4 v = ((const float4*)(x + (size_t)s * IN_C))[q];
            g.x += v.x; g.y += v.y; g.z += v.z; g.w += v.w;
        }
        #pragma unroll
        for (int m = 2; m <= 32; m <<= 1) {
            g.x += __shfl_xor(g.x, m);
            g.y += __shfl_xor(g.y, m);
            g.z += __shfl_xor(g.z, m);
            g.w += __shfl_xor(g.w, m);
        }
        g.x *= icnt; g.y *= icnt; g.z *= icnt; g.w *= icnt;
        float4 o;
        o.x = __shfl_xor(g.x, 1);
        o.y = __shfl_xor(g.y, 1);
        o.z = __shfl_xor(g.z, 1);
        o.w = __shfl_xor(g.w, 1);
        float4 mka = q ? o : g;   // mean channels 0-3
        float4 mkb = q ? g : o;   // mean channels 4-7

        // h = relu(mean @ W1l.T + b1 + x @ W1r.T), two accumulator chains
        float4 xa = *(const float4*)(x + (size_t)n * IN_C);
        float4 xb = *(const float4*)(x + (size_t)n * IN_C + 4);
        float ha = bias1 + mka.x * w1l_a.x + xa.x * w1r_a.x
                         + mka.z * w1l_a.z + xa.z * w1r_a.z
                         + mkb.x * w1l_b.x + xb.x * w1r_b.x
                         + mkb.z * w1l_b.z + xb.z * w1r_b.z;
        float hb = mka.y * w1l_a.y + xa.y * w1r_a.y
                 + mka.w * w1l_a.w + xa.w * w1r_a.w
                 + mkb.y * w1l_b.y + xb.y * w1r_b.y
                 + mkb.w * w1l_b.w + xb.w * w1r_b.w;
        float h = fmaxf(ha + hb, 0.0f);
        hl[w][l] = h;   // wave-local, in-order DS: no barrier

        // W2 dot: 4 independent chains over 16 h-quads
        float a0 = bias2, a1 = 0.f, a2 = 0.f, a3 = 0.f;
        #pragma unroll
        for (int r = 0; r < 16; r += 4) {
            float4 h0 = *(const float4*)&hl[w][r * 4];
            float4 h1 = *(const float4*)&hl[w][r * 4 + 4];
            float4 h2 = *(const float4*)&hl[w][r * 4 + 8];
            float4 h3 = *(const float4*)&hl[w][r * 4 + 12];
            a0 += h0.x * w2q[r].x + h0.y * w2q[r].y + h0.z * w2q[r].z + h0.w * w2q[r].w;
            a1 += h1.x * w2q[r+1].x + h1.y * w2q[r+1].y + h1.z * w2q[r+1].z + h1.w * w2q[r+1].w;
            a2 += h2.x * w2q[r+2].x + h2.y * w2q[r+2].y + h2.z * w2q[r+2].z + h2.w * w2q[r+2].w;
            a3 += h3.x * w2q[r+3].x + h3.y * w2q[r+3].y + h3.z * w2q[r+3].z + h3.w * w2q[r+3].w;
        }
        dstp[(size_t)n * OUT_C + c] = (a0 + a1) + (a2 + a3);
    }
}

// ---------------------------------------------------------------------------
// K5: layer-2 neighbor gather. One wave per node, grid-strided.
// lane = (slot = l>>2 in 0..15, h2 = l&3): each lane 2 independent float4
// loads covering 32B of the 128B p-row; deg<=16 -> ONE gather iteration.
// 4-level xor reduce; lanes 0-3 RMW the out row.
// ---------------------------------------------------------------------------
__global__ __launch_bounds__(256) void layer2_kernel(
    const float* __restrict__ p, const int* __restrict__ csr_src,
    const int* __restrict__ base, const int* __restrict__ cnt,
    float* __restrict__ out, int N, int nwaves)
{
    int tid = threadIdx.x;
    int w = tid >> 6;
    int l = tid & 63;
    int waveId = blockIdx.x * 4 + w;
    int slot = l >> 2;
    int h2 = l & 3;

    for (int n = waveId; n < N; n += nwaves) {
        int deg = cnt[n];
        int b0 = base[n];
        float4 ga = make_float4(0.f, 0.f, 0.f, 0.f);
        float4 gb = make_float4(0.f, 0.f, 0.f, 0.f);
        for (int it = slot; it < deg; it += 16) {
            int s = csr_src[b0 + it];
            const float4* pr = (const float4*)(p + (size_t)s * OUT_C) + h2 * 2;
            float4 va = pr[0];
            float4 vb = pr[1];
            ga.x += va.x; ga.y += va.y; ga.z += va.z; ga.w += va.w;
            gb.x += vb.x; gb.y += vb.y; gb.z += vb.z; gb.w += vb.w;
        }
        #pragma unroll
        for (int m = 4; m <= 32; m <<= 1) {
            ga.x += __shfl_xor(ga.x, m); ga.y += __shfl_xor(ga.y, m);
            ga.z += __shfl_xor(ga.z, m); ga.w += __shfl_xor(ga.w, m);
            gb.x += __shfl_xor(gb.x, m); gb.y += __shfl_xor(gb.y, m);
            gb.z += __shfl_xor(gb.z, m); gb.w += __shfl_xor(gb.w, m);
        }
        if (l < 4) {
            float icnt = 1.0f / (float)max(deg, 1);
            float4* op = (float4*)(out + (size_t)n * OUT_C) + h2 * 2;
            float4 oa = op[0];
            float4 ob = op[1];
            oa.x += ga.x * icnt; oa.y += ga.y * icnt;
            oa.z += ga.z * icnt; oa.w += ga.w * icnt;
            ob.x += gb.x * icnt; ob.y += gb.y * icnt;
            ob.z += gb.z * icnt; ob.w += gb.w * icnt;
            op[0] = oa;
            op[1] = ob;
        }
    }
}

extern "C" void kernel_launch(void* const* d_in, const int* in_sizes, int n_in,
                              void* d_out, int out_size, void* d_ws, size_t ws_size,
                              hipStream_t stream) {
    const float* x   = (const float*)d_in[0];
    const int*   ei  = (const int*)d_in[1];
    const float* W1l = (const float*)d_in[2];
    const float* W1r = (const float*)d_in[3];
    const float* b1  = (const float*)d_in[4];
    const float* W2l = (const float*)d_in[5];
    const float* W2r = (const float*)d_in[6];
    const float* b2  = (const float*)d_in[7];
    float* out = (float*)d_out;

    int N = in_sizes[0] / IN_C;
    int E = in_sizes[1] / 2;
    const int* src = ei;
    const int* dst = ei + E;

    // Workspace: cnt[N] | cursor[1] | base[N] | wpos[N] | csr_src[E] | p[N*32]
    char* ws = (char*)d_ws;
    size_t off = 0;
    int*   cnt     = (int*)(ws + off); off += (size_t)N * 4;
    int*   cursor  = (int*)(ws + off); off += 4;
    int*   base    = (int*)(ws + off); off += (size_t)N * 4;
    int*   wpos    = (int*)(ws + off); off += (size_t)N * 4;
    int*   csr_src = (int*)(ws + off); off += (size_t)E * 4;
    float* p       = (float*)(ws + off);

    hipMemsetAsync(d_ws, 0, (size_t)(N + 1) * 4, stream);

    const int blk = 256;
    const int nblocks = 4096;
    const int nwaves = nblocks * 4;

    hist_kernel<<<(E / 4 + blk - 1) / blk, blk, 0, stream>>>(dst, cnt, E);
    base_kernel<<<(N + blk - 1) / blk, blk, 0, stream>>>(cnt, base, wpos, cursor, N);
    fill_kernel<<<(E / 4 + blk - 1) / blk, blk, 0, stream>>>(src, dst, wpos, csr_src, E);
    layer1_kernel<<<nblocks, blk, 0, stream>>>(x, csr_src, base, cnt,
                                               W1l, W1r, b1, W2l, W2r, b2,
                                               p, out, N, nwaves);
    layer2_kernel<<<nblocks, blk, 0, stream>>>(p, csr_src, base, cnt, out, N, nwaves);
}

// Round 5
// 282.650 us; speedup vs baseline: 5.6599x; 1.2148x over previous
//
#include <hip/hip_runtime.h>

#define IN_C 8
#define HID_C 64
#define OUT_C 32

// ---------------------------------------------------------------------------
// K1: histogram of dst degrees; records each edge's rank within its dst
// segment (returning atomic), written coalesced to erank[].
// ---------------------------------------------------------------------------
__global__ __launch_bounds__(256) void hist_kernel(
    const int* __restrict__ dst, int* __restrict__ cnt,
    int* __restrict__ erank, int E)
{
    int i = blockIdx.x * blockDim.x + threadIdx.x;
    int e0 = i * 4;
    if (e0 + 3 < E) {
        int4 d4 = *(const int4*)(dst + e0);
        int4 r;
        r.x = atomicAdd(&cnt[d4.x], 1);
        r.y = atomicAdd(&cnt[d4.y], 1);
        r.z = atomicAdd(&cnt[d4.z], 1);
        r.w = atomicAdd(&cnt[d4.w], 1);
        *(int4*)(erank + e0) = r;
    } else {
        for (int e = e0; e < E; ++e)
            erank[e] = atomicAdd(&cnt[dst[e]], 1);
    }
}

// ---------------------------------------------------------------------------
// K2: CSR segment bases via wave-scan + one cursor atomic per wave.
// ---------------------------------------------------------------------------
__global__ __launch_bounds__(256) void base_kernel(
    const int* __restrict__ cnt, int* __restrict__ base,
    int* __restrict__ cursor, int N)
{
    int n = blockIdx.x * blockDim.x + threadIdx.x;
    int lane = threadIdx.x & 63;
    int c = (n < N) ? cnt[n] : 0;

    int v = c;
    #pragma unroll
    for (int off = 1; off < 64; off <<= 1) {
        int t = __shfl_up(v, off);
        if (lane >= off) v += t;
    }
    int total = __shfl(v, 63);
    int waveBase = 0;
    if (lane == 63 && total > 0) waveBase = atomicAdd(cursor, total);
    waveBase = __shfl(waveBase, 63);

    if (n < N) base[n] = waveBase + v - c;
}

// ---------------------------------------------------------------------------
// K3: fill CSR adjacency — atomic-free scatter: pos = base[dst] + erank.
// Non-temporal stores keep the scattered 4B writes out of the writer-XCD's
// L2 (avoids cross-XCD dirty-line ping-pong).
// ---------------------------------------------------------------------------
__global__ __launch_bounds__(256) void fill_kernel(
    const int* __restrict__ src, const int* __restrict__ dst,
    const int* __restrict__ erank, const int* __restrict__ base,
    int* __restrict__ csr_src, int E)
{
    int i = blockIdx.x * blockDim.x + threadIdx.x;
    int e0 = i * 4;
    if (e0 + 3 < E) {
        int4 s4 = *(const int4*)(src + e0);
        int4 d4 = *(const int4*)(dst + e0);
        int4 r4 = *(const int4*)(erank + e0);
        __builtin_nontemporal_store(s4.x, &csr_src[base[d4.x] + r4.x]);
        __builtin_nontemporal_store(s4.y, &csr_src[base[d4.y] + r4.y]);
        __builtin_nontemporal_store(s4.z, &csr_src[base[d4.z] + r4.z]);
        __builtin_nontemporal_store(s4.w, &csr_src[base[d4.w] + r4.w]);
    } else {
        for (int e = e0; e < E; ++e)
            __builtin_nontemporal_store(src[e], &csr_src[base[dst[e]] + erank[e]]);
    }
}

// ---------------------------------------------------------------------------
// K4: fused layer-1 + both layer-2 projections. One wave per node,
// grid-strided, NO BARRIERS (hl[w] is wave-local).
// ---------------------------------------------------------------------------
__global__ __launch_bounds__(256) void layer1_kernel(
    const float* __restrict__ x, const int* __restrict__ csr_src,
    const int* __restrict__ base, const int* __restrict__ cnt,
    const float* __restrict__ W1l, const float* __restrict__ W1r,
    const float* __restrict__ b1,
    const float* __restrict__ W2l, const float* __restrict__ W2r,
    const float* __restrict__ b2,
    float* __restrict__ p, float* __restrict__ out, int N, int nwaves)
{
    __shared__ float hl[4][HID_C];
    int tid = threadIdx.x;
    int w = tid >> 6;
    int l = tid & 63;
    int waveId = blockIdx.x * 4 + w;

    float4 w1l_a = *(const float4*)(W1l + l * IN_C);
    float4 w1l_b = *(const float4*)(W1l + l * IN_C + 4);
    float4 w1r_a = *(const float4*)(W1r + l * IN_C);
    float4 w1r_b = *(const float4*)(W1r + l * IN_C + 4);
    int c = l & 31;
    const float* W2 = (l < 32) ? W2l : W2r;
    float4 w2q[16];
    #pragma unroll
    for (int r = 0; r < 16; ++r)
        w2q[r] = *(const float4*)(W2 + c * HID_C + r * 4);
    float bias1 = b1[l];
    float bias2 = (l < 32) ? 0.0f : b2[c];
    float* dstp = (l < 32) ? p : out;

    int slot = l >> 1;
    int q = l & 1;

    for (int n = waveId; n < N; n += nwaves) {
        int deg = cnt[n];
        int b0 = base[n];
        float icnt = 1.0f / (float)max(deg, 1);

        float4 g = make_float4(0.f, 0.f, 0.f, 0.f);
        for (int it = slot; it < deg; it += 32) {
            int s = csr_src[b0 + it];
            float4 v = ((const float4*)(x + (size_t)s * IN_C))[q];
            g.x += v.x; g.y += v.y; g.z += v.z; g.w += v.w;
        }
        #pragma unroll
        for (int m = 2; m <= 32; m <<= 1) {
            g.x += __shfl_xor(g.x, m);
            g.y += __shfl_xor(g.y, m);
            g.z += __shfl_xor(g.z, m);
            g.w += __shfl_xor(g.w, m);
        }
        g.x *= icnt; g.y *= icnt; g.z *= icnt; g.w *= icnt;
        float4 o;
        o.x = __shfl_xor(g.x, 1);
        o.y = __shfl_xor(g.y, 1);
        o.z = __shfl_xor(g.z, 1);
        o.w = __shfl_xor(g.w, 1);
        float4 mka = q ? o : g;
        float4 mkb = q ? g : o;

        float4 xa = *(const float4*)(x + (size_t)n * IN_C);
        float4 xb = *(const float4*)(x + (size_t)n * IN_C + 4);
        float ha = bias1 + mka.x * w1l_a.x + xa.x * w1r_a.x
                         + mka.z * w1l_a.z + xa.z * w1r_a.z
                         + mkb.x * w1l_b.x + xb.x * w1r_b.x
                         + mkb.z * w1l_b.z + xb.z * w1r_b.z;
        float hb = mka.y * w1l_a.y + xa.y * w1r_a.y
                 + mka.w * w1l_a.w + xa.w * w1r_a.w
                 + mkb.y * w1l_b.y + xb.y * w1r_b.y
                 + mkb.w * w1l_b.w + xb.w * w1r_b.w;
        float h = fmaxf(ha + hb, 0.0f);
        hl[w][l] = h;

        float a0 = bias2, a1 = 0.f, a2 = 0.f, a3 = 0.f;
        #pragma unroll
        for (int r = 0; r < 16; r += 4) {
            float4 h0 = *(const float4*)&hl[w][r * 4];
            float4 h1 = *(const float4*)&hl[w][r * 4 + 4];
            float4 h2 = *(const float4*)&hl[w][r * 4 + 8];
            float4 h3 = *(const float4*)&hl[w][r * 4 + 12];
            a0 += h0.x * w2q[r].x + h0.y * w2q[r].y + h0.z * w2q[r].z + h0.w * w2q[r].w;
            a1 += h1.x * w2q[r+1].x + h1.y * w2q[r+1].y + h1.z * w2q[r+1].z + h1.w * w2q[r+1].w;
            a2 += h2.x * w2q[r+2].x + h2.y * w2q[r+2].y + h2.z * w2q[r+2].z + h2.w * w2q[r+2].w;
            a3 += h3.x * w2q[r+3].x + h3.y * w2q[r+3].y + h3.z * w2q[r+3].z + h3.w * w2q[r+3].w;
        }
        dstp[(size_t)n * OUT_C + c] = (a0 + a1) + (a2 + a3);
    }
}

// ---------------------------------------------------------------------------
// K5: layer-2 neighbor gather. One wave per node, grid-strided.
// ---------------------------------------------------------------------------
__global__ __launch_bounds__(256) void layer2_kernel(
    const float* __restrict__ p, const int* __restrict__ csr_src,
    const int* __restrict__ base, const int* __restrict__ cnt,
    float* __restrict__ out, int N, int nwaves)
{
    int tid = threadIdx.x;
    int w = tid >> 6;
    int l = tid & 63;
    int waveId = blockIdx.x * 4 + w;
    int slot = l >> 2;
    int h2 = l & 3;

    for (int n = waveId; n < N; n += nwaves) {
        int deg = cnt[n];
        int b0 = base[n];
        float4 ga = make_float4(0.f, 0.f, 0.f, 0.f);
        float4 gb = make_float4(0.f, 0.f, 0.f, 0.f);
        for (int it = slot; it < deg; it += 16) {
            int s = csr_src[b0 + it];
            const float4* pr = (const float4*)(p + (size_t)s * OUT_C) + h2 * 2;
            float4 va = pr[0];
            float4 vb = pr[1];
            ga.x += va.x; ga.y += va.y; ga.z += va.z; ga.w += va.w;
            gb.x += vb.x; gb.y += vb.y; gb.z += vb.z; gb.w += vb.w;
        }
        #pragma unroll
        for (int m = 4; m <= 32; m <<= 1) {
            ga.x += __shfl_xor(ga.x, m); ga.y += __shfl_xor(ga.y, m);
            ga.z += __shfl_xor(ga.z, m); ga.w += __shfl_xor(ga.w, m);
            gb.x += __shfl_xor(gb.x, m); gb.y += __shfl_xor(gb.y, m);
            gb.z += __shfl_xor(gb.z, m); gb.w += __shfl_xor(gb.w, m);
        }
        if (l < 4) {
            float icnt = 1.0f / (float)max(deg, 1);
            float4* op = (float4*)(out + (size_t)n * OUT_C) + h2 * 2;
            float4 oa = op[0];
            float4 ob = op[1];
            oa.x += ga.x * icnt; oa.y += ga.y * icnt;
            oa.z += ga.z * icnt; oa.w += ga.w * icnt;
            ob.x += gb.x * icnt; ob.y += gb.y * icnt;
            ob.z += gb.z * icnt; ob.w += gb.w * icnt;
            op[0] = oa;
            op[1] = ob;
        }
    }
}

extern "C" void kernel_launch(void* const* d_in, const int* in_sizes, int n_in,
                              void* d_out, int out_size, void* d_ws, size_t ws_size,
                              hipStream_t stream) {
    const float* x   = (const float*)d_in[0];
    const int*   ei  = (const int*)d_in[1];
    const float* W1l = (const float*)d_in[2];
    const float* W1r = (const float*)d_in[3];
    const float* b1  = (const float*)d_in[4];
    const float* W2l = (const float*)d_in[5];
    const float* W2r = (const float*)d_in[6];
    const float* b2  = (const float*)d_in[7];
    float* out = (float*)d_out;

    int N = in_sizes[0] / IN_C;
    int E = in_sizes[1] / 2;
    const int* src = ei;
    const int* dst = ei + E;

    // Workspace: cnt[N] | cursor[1] | base[N] | erank[E] | csr_src[E] | p[N*32]
    char* ws = (char*)d_ws;
    size_t off = 0;
    int*   cnt     = (int*)(ws + off); off += (size_t)N * 4;
    int*   cursor  = (int*)(ws + off); off += 4;
    int*   base    = (int*)(ws + off); off += (size_t)N * 4;
    int*   erank   = (int*)(ws + off); off += (size_t)E * 4;
    int*   csr_src = (int*)(ws + off); off += (size_t)E * 4;
    float* p       = (float*)(ws + off);

    hipMemsetAsync(d_ws, 0, (size_t)(N + 1) * 4, stream);

    const int blk = 256;
    const int nblocks = 4096;
    const int nwaves = nblocks * 4;

    hist_kernel<<<(E / 4 + blk - 1) / blk, blk, 0, stream>>>(dst, cnt, erank, E);
    base_kernel<<<(N + blk - 1) / blk, blk, 0, stream>>>(cnt, base, cursor, N);
    fill_kernel<<<(E / 4 + blk - 1) / blk, blk, 0, stream>>>(src, dst, erank, base, csr_src, E);
    layer1_kernel<<<nblocks, blk, 0, stream>>>(x, csr_src, base, cnt,
                                               W1l, W1r, b1, W2l, W2r, b2,
                                               p, out, N, nwaves);
    layer2_kernel<<<nblocks, blk, 0, stream>>>(p, csr_src, base, cnt, out, N, nwaves);
}